// Round 6
// baseline (148.736 us; speedup 1.0000x reference)
//
#include <hip/hip_runtime.h>
#include <math.h>

// Problem constants
constexpr float BCONST      = 0.9f;
constexpr float ONE_MINUS_B = 0.1f;
constexpr float EPSF        = 1e-10f;
constexpr float SCALEF      = 0.0625f;   // 1/sqrt(256), exact power of 2

// Workspace layout (float offsets) — R0 layout
#define OFF_QKV    0
#define OFF_VP     786432
#define OFF_EW     1048576
#define OFF_PMIN   1310720
#define OFF_PMAX   1318912
#define OFF_VMIN   1327104
#define OFF_VRANGE 1327616
#define OFF_P      1328128

// Swizzled chunk buffer: row-major LD=32 floats, bank-quad ^= (row>>2)&7.
#define KB4(buf, row, col4) \
  (&(buf)[((row) << 5) | ((((col4) >> 2) ^ (((row) >> 2) & 7)) << 2)])

// ---------------------------------------------------------------------------
// Tiled fp32 GEMM: C[i][j] = dot(A[i,:K], Brow(j)).
// NT = threads/block (staging guarded to tile rows, so NT may exceed the
// 256-thread staging footprint). Per-output k-accumulation order is fixed
// regardless of NT/RM/RN -> results bit-identical across configs.
// MM=true: V-column blocks (j0>=512) also write per-row-tile min/max partials.
// ---------------------------------------------------------------------------
template<int NT, int TM, int TN, int RM, int RN, bool MM>
__global__ __launch_bounds__(NT) void gemm_t(
    const float* __restrict__ A, const float* __restrict__ B0,
    const float* __restrict__ B1, int nsplit,
    float* __restrict__ C, int ldc, int K, int lda,
    float* __restrict__ pminP, float* __restrict__ pmaxP) {
  constexpr int LDT = 36;
  constexpr int CG  = TN / RN;
  __shared__ float As[TM][LDT];
  __shared__ float Bs[TN][LDT];
  const int i0 = blockIdx.x * TM;
  const int j0 = blockIdx.y * TN;
  const float* Bsrc = (j0 < nsplit) ? (B0 + (size_t)j0 * K)
                                    : (B1 + (size_t)(j0 - nsplit) * K);
  const int t  = threadIdx.x;
  const int lr = t >> 3;
  const int lc = (t & 7) << 2;
  const int tx = t % CG, ty = t / CG;

  float4 pa, pb;
  if (lr < TM) pa = *(const float4*)(A + (size_t)(i0 + lr) * lda + lc);
  if (lr < TN) pb = *(const float4*)(Bsrc + (size_t)lr * K + lc);

  float acc[RM][RN] = {};
  for (int k0 = 0; k0 < K; k0 += 32) {
    __syncthreads();
    if (lr < TM) *(float4*)&As[lr][lc] = pa;
    if (lr < TN) *(float4*)&Bs[lr][lc] = pb;
    __syncthreads();
    if (k0 + 32 < K) {
      if (lr < TM) pa = *(const float4*)(A + (size_t)(i0 + lr) * lda + k0 + 32 + lc);
      if (lr < TN) pb = *(const float4*)(Bsrc + (size_t)lr * K + k0 + 32 + lc);
    }
#pragma unroll
    for (int kk = 0; kk < 32; kk += 4) {
      float4 af[RM], bf[RN];
#pragma unroll
      for (int r = 0; r < RM; ++r) af[r] = *(const float4*)&As[ty * RM + r][kk];
#pragma unroll
      for (int c = 0; c < RN; ++c) bf[c] = *(const float4*)&Bs[tx + CG * c][kk];
#pragma unroll
      for (int r = 0; r < RM; ++r)
#pragma unroll
        for (int c = 0; c < RN; ++c)
          acc[r][c] += af[r].x * bf[c].x + af[r].y * bf[c].y +
                       af[r].z * bf[c].z + af[r].w * bf[c].w;
    }
  }
#pragma unroll
  for (int r = 0; r < RM; ++r)
#pragma unroll
    for (int c = 0; c < RN; ++c)
      C[(size_t)(i0 + ty * RM + r) * ldc + j0 + tx + CG * c] = acc[r][c];

  if (MM && j0 >= 512) {
    __syncthreads();
    float* mnb = &As[0][0];
    float* mxb = &Bs[0][0];
#pragma unroll
    for (int c = 0; c < RN; ++c) {
      float mn = acc[0][c], mx = acc[0][c];
#pragma unroll
      for (int r = 1; r < RM; ++r) {
        mn = fminf(mn, acc[r][c]);
        mx = fmaxf(mx, acc[r][c]);
      }
      mnb[(tx + CG * c) * 17 + ty] = mn;
      mxb[(tx + CG * c) * 17 + ty] = mx;
    }
    __syncthreads();
    if (t < TN) {
      float mn = mnb[t * 17], mx = mxb[t * 17];
#pragma unroll
      for (int i = 1; i < 16; ++i) {
        mn = fminf(mn, mnb[t * 17 + i]);
        mx = fmaxf(mx, mxb[t * 17 + i]);
      }
      const int bx = i0 >> 5;          // row-tile 0..31
      pminP[bx * 256 + (j0 - 512) + t] = mn;
      pmaxP[bx * 256 + (j0 - 512) + t] = mx;
    }
  }
}

// ---------------------------------------------------------------------------
// vp = expm1(p * log(v_norm)); also vmin / vrange per (b,d) and pw. (R0 exact)
// ---------------------------------------------------------------------------
__global__ __launch_bounds__(256) void vpk(
    const float* __restrict__ qkv, const float* __restrict__ pminP,
    const float* __restrict__ pmaxP, const float* __restrict__ p_param,
    float* __restrict__ vp, float* __restrict__ vminw,
    float* __restrict__ vrangew, float* __restrict__ pw) {
  const int blk = blockIdx.x;           // 0..1023
  const int b = blk >> 9, s = blk & 511;
  const int d = threadIdx.x;
  float mn = pminP[(b * 16) * 256 + d];
  float mx = pmaxP[(b * 16) * 256 + d];
#pragma unroll
  for (int c = 1; c < 16; ++c) {
    mn = fminf(mn, pminP[(b * 16 + c) * 256 + d]);
    mx = fmaxf(mx, pmaxP[(b * 16 + c) * 256 + d]);
  }
  float p = 50000.0f * tanhf(0.005f * p_param[d]) + 1.0f;
  if (p == 0.0f) p = 0.0001f;
  const float range = mx - mn + EPSF;
  const float v  = qkv[((size_t)(b * 512 + s)) * 768 + 512 + d];
  const float vn = (ONE_MINUS_B * (v - mn)) / range + BCONST;
  vp[(size_t)blk * 256 + d] = expm1f(p * logf(vn));
  if (s == 0) { vminw[b * 256 + d] = mn; vrangew[b * 256 + d] = range; }
  if (blk == 0) pw[d] = p;
}

// ---------------------------------------------------------------------------
// Fused attention — R0 math, 1024 threads (16 waves/CU = 4/SIMD, was 2/SIMD).
// Phase 1: thread = 2q (w+16r) x 8k; per-lane e-partial ordering and the
//          64-lane butterfly are IDENTICAL to R0 -> scores/T bit-identical.
// Phase 3: thread = 4q x 4a, wave-uniform 16-way k-slices (32 k each, same
//          in-slice accumulation order); 16 slice-partials folded through LDS
//          (`part` overlays qs+sc+kb-head, all dead at that point).
// grid = (S/32, B*H), 1 block/CU (136 KB LDS).
// ---------------------------------------------------------------------------
__global__ __launch_bounds__(1024) void attn_k(
    const float* __restrict__ qkv, const float* __restrict__ vp,
    const float* __restrict__ pw, const float* __restrict__ vminw,
    const float* __restrict__ vrangew, float* __restrict__ ew) {
  __shared__ float S[34080];           // 136.3 KB total
  float* qs  = S;                      // [32][36]
  float* sc  = S + 1152;               // [32][516] unnormalized softmax e
  float* kb  = S + 17664;              // [512][32] swizzled K / VP panel
  float* red = S + 34048;              // [32] per-row sum T
  float* part = S;                     // [16][32*36] (overlays qs,sc,kb head)
  const int bh  = blockIdx.y;
  const int b   = bh >> 3, h = bh & 7;
  const int q0g = blockIdx.x * 32;
  const int t   = threadIdx.x;
  const int srow = t >> 3, scol4 = (t & 7) << 2;   // srow 0..127

  // q tile (32 x 32), fold in SCALE (exact *2^-4)
  if (t < 256) {
    const int q = t >> 3, c4 = (t & 7) << 2;
    float4 qv = *(const float4*)(qkv + ((size_t)(b * 512 + q0g + q)) * 768 + h * 32 + c4);
    qv.x *= SCALEF; qv.y *= SCALEF; qv.z *= SCALEF; qv.w *= SCALEF;
    *(float4*)&qs[q * 36 + c4] = qv;
  }
  // stage FULL K panel (512 rows, 128 rows per sweep)
#pragma unroll
  for (int u = 0; u < 4; ++u) {
    const int r = srow + 128 * u;
    float4 v = *(const float4*)(qkv + ((size_t)(b * 512 + r)) * 768 + 256 + h * 32 + scol4);
    *(float4*)KB4(kb, r, scol4) = v;
  }
  __syncthreads();

  // ---- Phase 1: scores + inline softmax. thread = 2q (w+16r) x 8k.
  {
    const int w  = t >> 6;             // wave id 0..15: wave-uniform q group
    const int kg = t & 63;             // k cols kg*4..+3 and 256+kg*4..+3
    float s8[2][8] = {};
#pragma unroll 2
    for (int kk = 0; kk < 32; kk += 4) {
      float4 qf[2], kf1[4], kf2[4];
#pragma unroll
      for (int r = 0; r < 2; ++r) qf[r] = *(const float4*)&qs[(w + 16 * r) * 36 + kk];
#pragma unroll
      for (int c = 0; c < 4; ++c) {
        kf1[c] = *(const float4*)KB4(kb, kg * 4 + c, kk);
        kf2[c] = *(const float4*)KB4(kb, 256 + kg * 4 + c, kk);
      }
#pragma unroll
      for (int r = 0; r < 2; ++r)
#pragma unroll
        for (int c = 0; c < 4; ++c) {
          s8[r][c]     += qf[r].x * kf1[c].x + qf[r].y * kf1[c].y +
                          qf[r].z * kf1[c].z + qf[r].w * kf1[c].w;
          s8[r][4 + c] += qf[r].x * kf2[c].x + qf[r].y * kf2[c].y +
                          qf[r].z * kf2[c].z + qf[r].w * kf2[c].w;
        }
    }
    // exp in registers + per-row local sums (same per-lane order as R0)
    float rs[2];
#pragma unroll
    for (int r = 0; r < 2; ++r) {
      float s = 0.f;
#pragma unroll
      for (int c = 0; c < 8; ++c) {
        s8[r][c] = __expf(s8[r][c]);
        s += s8[r][c];
      }
      rs[r] = s;
    }
    // wave butterfly: full row sums (row w+16r owned entirely by wave w)
#pragma unroll
    for (int m = 1; m < 64; m <<= 1)
#pragma unroll
      for (int r = 0; r < 2; ++r) rs[r] += __shfl_xor(rs[r], m);
    if ((t & 63) == 0)
#pragma unroll
      for (int r = 0; r < 2; ++r) red[w + 16 * r] = rs[r];
    // write unnormalized e
#pragma unroll
    for (int r = 0; r < 2; ++r) {
      const int rq = w + 16 * r;
      *(float4*)&sc[rq * 516 + kg * 4] =
          make_float4(s8[r][0], s8[r][1], s8[r][2], s8[r][3]);
      *(float4*)&sc[rq * 516 + 256 + kg * 4] =
          make_float4(s8[r][4], s8[r][5], s8[r][6], s8[r][7]);
    }
  }
  __syncthreads();                     // sc/red done; kb K-reads done

  // ---- stage FULL VP panel into kb
#pragma unroll
  for (int u = 0; u < 4; ++u) {
    const int r = srow + 128 * u;
    float4 v = *(const float4*)(vp + ((size_t)(b * 512 + r)) * 256 + h * 32 + scol4);
    *(float4*)KB4(kb, r, scol4) = v;
  }
  __syncthreads();

  // ---- Phase 3: ACC[q][a] = sum_k e[q][k]*vp[k][a]; thread = 4q x 4a,
  // wave-uniform 16-way k-split (32 k per slice, slice = wave id).
  const int lane = t & 63;
  const int ag = lane & 7;             // a cols ag*4..+3
  const int qg = lane >> 3;            // q rows qg+8r
  const int ks = t >> 6;               // 0..15, wave-uniform
  float a3[4][4] = {};
#pragma unroll
  for (int g = 0; g < 8; ++g) {
    const int kbase = ks * 32 + g * 4;
    float4 sq[4], vf[4];
#pragma unroll
    for (int r = 0; r < 4; ++r)
      sq[r] = *(const float4*)&sc[(qg + 8 * r) * 516 + kbase];
#pragma unroll
    for (int c = 0; c < 4; ++c)
      vf[c] = *(const float4*)KB4(kb, kbase + c, ag * 4);
#pragma unroll
    for (int r = 0; r < 4; ++r) {
      a3[r][0] += sq[r].x * vf[0].x + sq[r].y * vf[1].x + sq[r].z * vf[2].x + sq[r].w * vf[3].x;
      a3[r][1] += sq[r].x * vf[0].y + sq[r].y * vf[1].y + sq[r].z * vf[2].y + sq[r].w * vf[3].y;
      a3[r][2] += sq[r].x * vf[0].z + sq[r].y * vf[1].z + sq[r].z * vf[2].z + sq[r].w * vf[3].z;
      a3[r][3] += sq[r].x * vf[0].w + sq[r].y * vf[1].w + sq[r].z * vf[2].w + sq[r].w * vf[3].w;
    }
  }
  __syncthreads();                     // all sc/kb reads done; overlay as part
#pragma unroll
  for (int r = 0; r < 4; ++r)
#pragma unroll
    for (int c = 0; c < 4; ++c)
      part[ks * 1152 + (qg + 8 * r) * 36 + ag * 4 + c] = a3[r][c];
  __syncthreads();

  // ---- final 16-slice reduction + robust power-mean epilogue (4 out/thr)
  if (t < 256) {
    const int q = t >> 3, a0 = (t & 7) << 2;
    const int d0 = h * 32 + a0;
    const float invT = 1.0f / red[q];
    float4 s0 = *(const float4*)&part[q * 36 + a0];
#pragma unroll
    for (int w = 1; w < 16; ++w) {
      float4 sw = *(const float4*)&part[w * 1152 + q * 36 + a0];
      s0.x += sw.x; s0.y += sw.y; s0.z += sw.z; s0.w += sw.w;
    }
    const float4 pp = *(const float4*)(pw + d0);
    const float4 vr = *(const float4*)(vrangew + b * 256 + d0);
    const float4 vm = *(const float4*)(vminw + b * 256 + d0);
    float4 o;
    o.x = (expf(log1pf(s0.x * invT) / pp.x) - BCONST) * vr.x / ONE_MINUS_B + vm.x;
    o.y = (expf(log1pf(s0.y * invT) / pp.y) - BCONST) * vr.y / ONE_MINUS_B + vm.y;
    o.z = (expf(log1pf(s0.z * invT) / pp.z) - BCONST) * vr.z / ONE_MINUS_B + vm.z;
    o.w = (expf(log1pf(s0.w * invT) / pp.w) - BCONST) * vr.w / ONE_MINUS_B + vm.w;
    *(float4*)(ew + ((size_t)(b * 512 + q0g + q)) * 256 + d0) = o;
  }
}

// ---------------------------------------------------------------------------
extern "C" void kernel_launch(void* const* d_in, const int* in_sizes, int n_in,
                              void* d_out, int out_size, void* d_ws, size_t ws_size,
                              hipStream_t stream) {
  const float* ctx  = (const float*)d_in[0];
  const float* WQ   = (const float*)d_in[1];
  const float* WKV  = (const float*)d_in[2];
  const float* WOUT = (const float*)d_in[3];
  const float* PP   = (const float*)d_in[4];
  float* ws      = (float*)d_ws;
  float* qkv     = ws + OFF_QKV;
  float* vp      = ws + OFF_VP;
  float* ew      = ws + OFF_EW;
  float* pminP   = ws + OFF_PMIN;
  float* pmaxP   = ws + OFF_PMAX;
  float* vminw   = ws + OFF_VMIN;
  float* vrangew = ws + OFF_VRANGE;
  float* pw      = ws + OFF_P;
  float* out     = (float*)d_out;

  // Fused Q|K|V projection + V min/max partials: 1024x768x256, 32x32 tiles
  // (768 blocks ~= 3/CU -> 12 waves/CU)
  gemm_t<256, 32, 32, 2, 2, true><<<dim3(32, 24), 256, 0, stream>>>(
      ctx, WQ, WKV, 256, qkv, 768, 256, 256, pminP, pmaxP);
  // expm1(p * log(v_norm)) + p vector + vmin/vrange (16 partials/batch)
  vpk<<<1024, 256, 0, stream>>>(qkv, pminP, pmaxP, PP, vp, vminw, vrangew, pw);
  // Fused attention, 1024 threads = 16 waves/CU (was 8)
  attn_k<<<dim3(16, 16), 1024, 0, stream>>>(qkv, vp, pw, vminw, vrangew, ew);
  // Output projection: 1024x256x256, 32x32 tiles, 512 threads = 8 waves/CU
  gemm_t<512, 32, 32, 2, 1, false><<<dim3(32, 8), 512, 0, stream>>>(
      ew, WOUT, WOUT, 1 << 30, out, 256, 256, 256, nullptr, nullptr);
}

// Round 7
// 101.218 us; speedup vs baseline: 1.4695x; 1.4695x over previous
//
#include <hip/hip_runtime.h>
#include <math.h>

// Problem constants
constexpr float BCONST      = 0.9f;
constexpr float ONE_MINUS_B = 0.1f;
constexpr float EPSF        = 1e-10f;
constexpr float SCALEF      = 0.0625f;   // 1/sqrt(256), exact power of 2

// Workspace layout (float offsets) — R0 layout
#define OFF_QKV    0
#define OFF_VP     786432
#define OFF_EW     1048576
#define OFF_PMIN   1310720
#define OFF_PMAX   1318912
#define OFF_VMIN   1327104
#define OFF_VRANGE 1327616
#define OFF_P      1328128

// Swizzled chunk buffer: row-major LD=32 floats, bank-quad ^= (row>>2)&7.
#define KB4(buf, row, col4) \
  (&(buf)[((row) << 5) | ((((col4) >> 2) ^ (((row) >> 2) & 7)) << 2)])

// ---------------------------------------------------------------------------
// Tiled fp32 GEMM: C[i][j] = dot(A[i,:K], Brow(j)).
// NT = threads/block (staging guarded to tile rows). Per-output k-accumulation
// order is fixed regardless of NT/RM/RN -> results bit-identical across cfgs.
// MM=true: V-column blocks (j0>=512) also write per-row-tile min/max partials.
// ---------------------------------------------------------------------------
template<int NT, int TM, int TN, int RM, int RN, bool MM>
__global__ __launch_bounds__(NT) void gemm_t(
    const float* __restrict__ A, const float* __restrict__ B0,
    const float* __restrict__ B1, int nsplit,
    float* __restrict__ C, int ldc, int K, int lda,
    float* __restrict__ pminP, float* __restrict__ pmaxP) {
  constexpr int LDT = 36;
  constexpr int CG  = TN / RN;
  __shared__ float As[TM][LDT];
  __shared__ float Bs[TN][LDT];
  const int i0 = blockIdx.x * TM;
  const int j0 = blockIdx.y * TN;
  const float* Bsrc = (j0 < nsplit) ? (B0 + (size_t)j0 * K)
                                    : (B1 + (size_t)(j0 - nsplit) * K);
  const int t  = threadIdx.x;
  const int lr = t >> 3;
  const int lc = (t & 7) << 2;
  const int tx = t % CG, ty = t / CG;

  float4 pa, pb;
  if (lr < TM) pa = *(const float4*)(A + (size_t)(i0 + lr) * lda + lc);
  if (lr < TN) pb = *(const float4*)(Bsrc + (size_t)lr * K + lc);

  float acc[RM][RN] = {};
  for (int k0 = 0; k0 < K; k0 += 32) {
    __syncthreads();
    if (lr < TM) *(float4*)&As[lr][lc] = pa;
    if (lr < TN) *(float4*)&Bs[lr][lc] = pb;
    __syncthreads();
    if (k0 + 32 < K) {
      if (lr < TM) pa = *(const float4*)(A + (size_t)(i0 + lr) * lda + k0 + 32 + lc);
      if (lr < TN) pb = *(const float4*)(Bsrc + (size_t)lr * K + k0 + 32 + lc);
    }
#pragma unroll
    for (int kk = 0; kk < 32; kk += 4) {
      float4 af[RM], bf[RN];
#pragma unroll
      for (int r = 0; r < RM; ++r) af[r] = *(const float4*)&As[ty * RM + r][kk];
#pragma unroll
      for (int c = 0; c < RN; ++c) bf[c] = *(const float4*)&Bs[tx + CG * c][kk];
#pragma unroll
      for (int r = 0; r < RM; ++r)
#pragma unroll
        for (int c = 0; c < RN; ++c)
          acc[r][c] += af[r].x * bf[c].x + af[r].y * bf[c].y +
                       af[r].z * bf[c].z + af[r].w * bf[c].w;
    }
  }
#pragma unroll
  for (int r = 0; r < RM; ++r)
#pragma unroll
    for (int c = 0; c < RN; ++c)
      C[(size_t)(i0 + ty * RM + r) * ldc + j0 + tx + CG * c] = acc[r][c];

  if (MM && j0 >= 512) {
    __syncthreads();
    float* mnb = &As[0][0];
    float* mxb = &Bs[0][0];
#pragma unroll
    for (int c = 0; c < RN; ++c) {
      float mn = acc[0][c], mx = acc[0][c];
#pragma unroll
      for (int r = 1; r < RM; ++r) {
        mn = fminf(mn, acc[r][c]);
        mx = fmaxf(mx, acc[r][c]);
      }
      mnb[(tx + CG * c) * 17 + ty] = mn;
      mxb[(tx + CG * c) * 17 + ty] = mx;
    }
    __syncthreads();
    if (t < TN) {
      float mn = mnb[t * 17], mx = mxb[t * 17];
#pragma unroll
      for (int i = 1; i < 16; ++i) {
        mn = fminf(mn, mnb[t * 17 + i]);
        mx = fmaxf(mx, mxb[t * 17 + i]);
      }
      const int bx = i0 >> 5;          // row-tile 0..31
      pminP[bx * 256 + (j0 - 512) + t] = mn;
      pmaxP[bx * 256 + (j0 - 512) + t] = mx;
    }
  }
}

// ---------------------------------------------------------------------------
// vp = expm1(p * log(v_norm)); also vmin / vrange per (b,d) and pw. (R0 exact)
// ---------------------------------------------------------------------------
__global__ __launch_bounds__(256) void vpk(
    const float* __restrict__ qkv, const float* __restrict__ pminP,
    const float* __restrict__ pmaxP, const float* __restrict__ p_param,
    float* __restrict__ vp, float* __restrict__ vminw,
    float* __restrict__ vrangew, float* __restrict__ pw) {
  const int blk = blockIdx.x;           // 0..1023
  const int b = blk >> 9, s = blk & 511;
  const int d = threadIdx.x;
  float mn = pminP[(b * 16) * 256 + d];
  float mx = pmaxP[(b * 16) * 256 + d];
#pragma unroll
  for (int c = 1; c < 16; ++c) {
    mn = fminf(mn, pminP[(b * 16 + c) * 256 + d]);
    mx = fmaxf(mx, pmaxP[(b * 16 + c) * 256 + d]);
  }
  float p = 50000.0f * tanhf(0.005f * p_param[d]) + 1.0f;
  if (p == 0.0f) p = 0.0001f;
  const float range = mx - mn + EPSF;
  const float v  = qkv[((size_t)(b * 512 + s)) * 768 + 512 + d];
  const float vn = (ONE_MINUS_B * (v - mn)) / range + BCONST;
  vp[(size_t)blk * 256 + d] = expm1f(p * logf(vn));
  if (s == 0) { vminw[b * 256 + d] = mn; vrangew[b * 256 + d] = range; }
  if (blk == 0) pw[d] = p;
}

// ---------------------------------------------------------------------------
// Fused attention — R5-proven 512-thread version (8 waves/CU, 2/SIMD).
// R6's 1024-thread variant spilled to scratch (launch_bounds VGPR cap ->
// ~240 MB HBM spill traffic, 65us); 512 threads keeps the 256-VGPR budget.
// Phase 1: thread = 4q (qgw+8r) x 8k, R0-identical partial order + butterfly.
// Phase 3: thread = 4q x 4a, wave-uniform 8-way k-slices folded through LDS.
// grid = (S/32, B*H), 1 block/CU (133 KB LDS).
// ---------------------------------------------------------------------------
__global__ __launch_bounds__(512) void attn_k(
    const float* __restrict__ qkv, const float* __restrict__ vp,
    const float* __restrict__ pw, const float* __restrict__ vminw,
    const float* __restrict__ vrangew, float* __restrict__ ew) {
  __shared__ float qs[32][36];
  __shared__ float sc[32 * 516];       // [q][k] unnormalized softmax e
  __shared__ float kb[512 * 32];       // swizzled K / VP panel (reused: part)
  __shared__ float red[32];            // per-row sum T
  const int bh  = blockIdx.y;
  const int b   = bh >> 3, h = bh & 7;
  const int q0g = blockIdx.x * 32;
  const int t   = threadIdx.x;
  const int srow = t >> 3, scol4 = (t & 7) << 2;   // srow 0..63

  // q tile (32 x 32), fold in SCALE (exact *2^-4)
  if (t < 256) {
    const int q = t >> 3, c4 = (t & 7) << 2;
    float4 qv = *(const float4*)(qkv + ((size_t)(b * 512 + q0g + q)) * 768 + h * 32 + c4);
    qv.x *= SCALEF; qv.y *= SCALEF; qv.z *= SCALEF; qv.w *= SCALEF;
    *(float4*)&qs[q][c4] = qv;
  }
  // stage FULL K panel (512 rows, 64 rows per sweep)
#pragma unroll 8
  for (int u = 0; u < 8; ++u) {
    const int r = srow + 64 * u;
    float4 v = *(const float4*)(qkv + ((size_t)(b * 512 + r)) * 768 + 256 + h * 32 + scol4);
    *(float4*)KB4(kb, r, scol4) = v;
  }
  __syncthreads();

  // ---- Phase 1: scores + inline softmax. thread = 4q (qgw+8r) x 8k.
  {
    const int qgw = t >> 6;            // wave id 0..7: wave-uniform q group
    const int kg  = t & 63;            // k cols kg*4..+3 and 256+kg*4..+3
    float s8[4][8] = {};
#pragma unroll 2
    for (int kk = 0; kk < 32; kk += 4) {
      float4 qf[4], kf1[4], kf2[4];
#pragma unroll
      for (int r = 0; r < 4; ++r) qf[r] = *(const float4*)&qs[qgw + 8 * r][kk];
#pragma unroll
      for (int c = 0; c < 4; ++c) {
        kf1[c] = *(const float4*)KB4(kb, kg * 4 + c, kk);
        kf2[c] = *(const float4*)KB4(kb, 256 + kg * 4 + c, kk);
      }
#pragma unroll
      for (int r = 0; r < 4; ++r)
#pragma unroll
        for (int c = 0; c < 4; ++c) {
          s8[r][c]     += qf[r].x * kf1[c].x + qf[r].y * kf1[c].y +
                          qf[r].z * kf1[c].z + qf[r].w * kf1[c].w;
          s8[r][4 + c] += qf[r].x * kf2[c].x + qf[r].y * kf2[c].y +
                          qf[r].z * kf2[c].z + qf[r].w * kf2[c].w;
        }
    }
    // exp in registers + per-row local sums
    float rs[4];
#pragma unroll
    for (int r = 0; r < 4; ++r) {
      float s = 0.f;
#pragma unroll
      for (int c = 0; c < 8; ++c) {
        s8[r][c] = __expf(s8[r][c]);
        s += s8[r][c];
      }
      rs[r] = s;
    }
    // wave butterfly: full row sums (row qgw+8r owned entirely by wave qgw)
#pragma unroll
    for (int m = 1; m < 64; m <<= 1)
#pragma unroll
      for (int r = 0; r < 4; ++r) rs[r] += __shfl_xor(rs[r], m);
    if ((t & 63) == 0)
#pragma unroll
      for (int r = 0; r < 4; ++r) red[qgw + 8 * r] = rs[r];
    // write unnormalized e
#pragma unroll
    for (int r = 0; r < 4; ++r) {
      const int rq = qgw + 8 * r;
      *(float4*)&sc[rq * 516 + kg * 4] =
          make_float4(s8[r][0], s8[r][1], s8[r][2], s8[r][3]);
      *(float4*)&sc[rq * 516 + 256 + kg * 4] =
          make_float4(s8[r][4], s8[r][5], s8[r][6], s8[r][7]);
    }
  }
  __syncthreads();                     // sc/red done; kb K-reads done

  // ---- stage FULL VP panel into kb
#pragma unroll 8
  for (int u = 0; u < 8; ++u) {
    const int r = srow + 64 * u;
    float4 v = *(const float4*)(vp + ((size_t)(b * 512 + r)) * 256 + h * 32 + scol4);
    *(float4*)KB4(kb, r, scol4) = v;
  }
  __syncthreads();

  // ---- Phase 3: ACC[q][a] = sum_k e[q][k]*vp[k][a]; thread = 4q x 4a,
  // wave-uniform 8-way k-split (64 k per slice, slice = wave id).
  const int ag = t & 7;                // a cols ag*4..+3
  const int qg = (t >> 3) & 7;         // q rows qg+8r
  const int ks = t >> 6;               // 0..7, wave-uniform
  float a3[4][4] = {};
#pragma unroll 2
  for (int g = 0; g < 16; ++g) {
    const int kbase = ks * 64 + g * 4;
    float4 sq[4], vf[4];
#pragma unroll
    for (int r = 0; r < 4; ++r)
      sq[r] = *(const float4*)&sc[(qg + 8 * r) * 516 + kbase];
#pragma unroll
    for (int c = 0; c < 4; ++c)
      vf[c] = *(const float4*)KB4(kb, kbase + c, ag * 4);
#pragma unroll
    for (int r = 0; r < 4; ++r) {
      a3[r][0] += sq[r].x * vf[0].x + sq[r].y * vf[1].x + sq[r].z * vf[2].x + sq[r].w * vf[3].x;
      a3[r][1] += sq[r].x * vf[0].y + sq[r].y * vf[1].y + sq[r].z * vf[2].y + sq[r].w * vf[3].y;
      a3[r][2] += sq[r].x * vf[0].z + sq[r].y * vf[1].z + sq[r].z * vf[2].z + sq[r].w * vf[3].z;
      a3[r][3] += sq[r].x * vf[0].w + sq[r].y * vf[1].w + sq[r].z * vf[2].w + sq[r].w * vf[3].w;
    }
  }
  __syncthreads();                     // kb reads done; reuse as part
  float* part = &kb[0];                // [8][32*36]
  {
#pragma unroll
    for (int r = 0; r < 4; ++r)
#pragma unroll
      for (int c = 0; c < 4; ++c)
        part[ks * 1152 + (qg + 8 * r) * 36 + ag * 4 + c] = a3[r][c];
  }
  __syncthreads();

  // ---- final 8-slice reduction + robust power-mean epilogue (4 outputs/thr)
  if (t < 256) {
    const int q = t >> 3, a0 = (t & 7) << 2;
    const int d0 = h * 32 + a0;
    const float invT = 1.0f / red[q];
    float4 s0 = *(const float4*)&part[q * 36 + a0];
#pragma unroll
    for (int w = 1; w < 8; ++w) {
      float4 sw = *(const float4*)&part[w * 1152 + q * 36 + a0];
      s0.x += sw.x; s0.y += sw.y; s0.z += sw.z; s0.w += sw.w;
    }
    const float4 pp = *(const float4*)(pw + d0);
    const float4 vr = *(const float4*)(vrangew + b * 256 + d0);
    const float4 vm = *(const float4*)(vminw + b * 256 + d0);
    float4 o;
    o.x = (expf(log1pf(s0.x * invT) / pp.x) - BCONST) * vr.x / ONE_MINUS_B + vm.x;
    o.y = (expf(log1pf(s0.y * invT) / pp.y) - BCONST) * vr.y / ONE_MINUS_B + vm.y;
    o.z = (expf(log1pf(s0.z * invT) / pp.z) - BCONST) * vr.z / ONE_MINUS_B + vm.z;
    o.w = (expf(log1pf(s0.w * invT) / pp.w) - BCONST) * vr.w / ONE_MINUS_B + vm.w;
    *(float4*)(ew + ((size_t)(b * 512 + q0g + q)) * 256 + d0) = o;
  }
}

// ---------------------------------------------------------------------------
extern "C" void kernel_launch(void* const* d_in, const int* in_sizes, int n_in,
                              void* d_out, int out_size, void* d_ws, size_t ws_size,
                              hipStream_t stream) {
  const float* ctx  = (const float*)d_in[0];
  const float* WQ   = (const float*)d_in[1];
  const float* WKV  = (const float*)d_in[2];
  const float* WOUT = (const float*)d_in[3];
  const float* PP   = (const float*)d_in[4];
  float* ws      = (float*)d_ws;
  float* qkv     = ws + OFF_QKV;
  float* vp      = ws + OFF_VP;
  float* ew      = ws + OFF_EW;
  float* pminP   = ws + OFF_PMIN;
  float* pmaxP   = ws + OFF_PMAX;
  float* vminw   = ws + OFF_VMIN;
  float* vrangew = ws + OFF_VRANGE;
  float* pw      = ws + OFF_P;
  float* out     = (float*)d_out;

  // Fused Q|K|V projection + V min/max partials: 1024x768x256, 32x32 tiles
  // (768 blocks ~= 3/CU -> 12 waves/CU)
  gemm_t<256, 32, 32, 2, 2, true><<<dim3(32, 24), 256, 0, stream>>>(
      ctx, WQ, WKV, 256, qkv, 768, 256, 256, pminP, pmaxP);
  // expm1(p * log(v_norm)) + p vector + vmin/vrange (16 partials/batch)
  vpk<<<1024, 256, 0, stream>>>(qkv, pminP, pmaxP, PP, vp, vminw, vrangew, pw);
  // Fused attention, 512 threads = 8 waves/CU (R5-proven; 1024 spills)
  attn_k<<<dim3(16, 16), 512, 0, stream>>>(qkv, vp, pw, vminw, vrangew, ew);
  // Output projection: 1024x256x256, 32x32 tiles, 512 threads = 8 waves/CU
  gemm_t<512, 32, 32, 2, 1, false><<<dim3(32, 8), 512, 0, stream>>>(
      ew, WOUT, WOUT, 1 << 30, out, 256, 256, 256, nullptr, nullptr);
}